// Round 2
// baseline (648.234 us; speedup 1.0000x reference)
//
#include <hip/hip_runtime.h>
#include <cstddef>
#include <cstdint>

#define NEGV -1e30f

constexpr int B_    = 32;
constexpr int TXT   = 256;
constexpr int MEL   = 2048;
constexpr int NMEL  = 80;

// ---------------------------------------------------------------------------
// Kernel P: per (b,j): iv[c]=exp(-logvar), m2[c]=2*mu*iv, s = sum(mu^2*iv + logvar)
// Writes IV/M2 transposed to [b][c][j] for coalesced LDS staging in kernel 1.
// ---------------------------------------------------------------------------
__global__ __launch_bounds__(256) void precompute_kernel(
    const float* __restrict__ mu_logvar,
    float* __restrict__ IV, float* __restrict__ M2, float* __restrict__ S)
{
    const int b = blockIdx.x;
    const int j = threadIdx.x;
    const float* row = mu_logvar + (size_t)(b * TXT + j) * (2 * NMEL);
    float s = 0.f;
    for (int c = 0; c < NMEL; ++c) {
        float mu = row[c];
        float lv = row[NMEL + c];
        float iv = expf(-lv);
        IV[(b * NMEL + c) * TXT + j] = iv;
        M2[(b * NMEL + c) * TXT + j] = 2.0f * mu * iv;
        s += mu * mu * iv + lv;
    }
    S[b * TXT + j] = s;
}

// ---------------------------------------------------------------------------
// Kernel 1: log_prob. Tile 64 j x 128 t per block (256 threads).
// Thread (tx,ty): tx in [0,16) (t), ty in [0,16) (j); computes 4 j x 8 t.
// Dual-writes: out[b][j][t] (at d_out+1) and lpT[b][t][j] in ws.
// ---------------------------------------------------------------------------
__global__ __launch_bounds__(256) void logprob_kernel(
    const float* __restrict__ mel,
    const float* __restrict__ IV, const float* __restrict__ M2,
    const float* __restrict__ S,
    float* __restrict__ out1,          // d_out + 1 (log_prob region)
    float* __restrict__ lpT,           // ws transposed copy [b][t][j]
    int write_lpT)
{
    const int tt0 = blockIdx.x * 128;
    const int j0  = blockIdx.y * 64;
    const int b   = blockIdx.z;
    const int tx  = threadIdx.x & 15;
    const int ty  = threadIdx.x >> 4;

    __shared__ float sIV[NMEL][64];
    __shared__ float sM2[NMEL][64];

    for (int idx = threadIdx.x; idx < NMEL * 64; idx += 256) {
        int c  = idx >> 6;
        int jj = idx & 63;
        sIV[c][jj] = IV[(b * NMEL + c) * TXT + j0 + jj];
        sM2[c][jj] = M2[(b * NMEL + c) * TXT + j0 + jj];
    }
    __syncthreads();

    float acc[4][8];
#pragma unroll
    for (int a = 0; a < 4; ++a)
#pragma unroll
        for (int d = 0; d < 8; ++d) acc[a][d] = 0.f;

    const float* melb = mel + (size_t)b * NMEL * MEL + tt0 + tx;

#pragma unroll 2
    for (int c = 0; c < NMEL; ++c) {
        float x[8];
#pragma unroll
        for (int d = 0; d < 8; ++d) x[d] = melb[(size_t)c * MEL + 16 * d];
        float4 iv = *(const float4*)&sIV[c][ty * 4];
        float4 m2 = *(const float4*)&sM2[c][ty * 4];
        float ivr[4] = {iv.x, iv.y, iv.z, iv.w};
        float m2r[4] = {m2.x, m2.y, m2.z, m2.w};
#pragma unroll
        for (int a = 0; a < 4; ++a) {
#pragma unroll
            for (int d = 0; d < 8; ++d) {
                float tmp = fmaf(ivr[a], x[d], -m2r[a]);
                acc[a][d] = fmaf(tmp, x[d], acc[a][d]);
            }
        }
    }

    const float c0 = -0.5f / (float)NMEL;
    float4 sj = *(const float4*)&S[b * TXT + j0 + ty * 4];
    float sjr[4] = {sj.x, sj.y, sj.z, sj.w};

#pragma unroll
    for (int a = 0; a < 4; ++a) {
        const int j = j0 + ty * 4 + a;
        float* ob = out1 + (size_t)(b * TXT + j) * MEL + tt0 + tx;
#pragma unroll
        for (int d = 0; d < 8; ++d) {
            float v = c0 * (acc[a][d] + sjr[a]);
            ob[16 * d] = v;
            if (write_lpT) {
                lpT[((size_t)b * MEL + tt0 + tx + 16 * d) * TXT + j] = v;
            }
        }
    }
}

// ---------------------------------------------------------------------------
// DP kernel v2: ONE WAVE per batch. Lane l holds j = {l, 64+l, 128+l, 192+l}
// (4 interleaved chunks). All j-1 dependencies are previous-step values:
//   chunk k lane l>0  <- cur[k][l-1]      : DPP wave_ror:1
//   chunk k lane 0    <- cur[k-1][63]     : wave_ror1(cur[k-1]) at lane 0
//   chunk 0 lane 0    <- NEGV
// No barriers, no LDS, no ds_permute. Coalesced loads from lpT[b][t][j],
// 8-deep register prefetch ring.
// ---------------------------------------------------------------------------
__device__ __forceinline__ float wave_ror1(float x) {
    int xi = __float_as_int(x);
    int r  = __builtin_amdgcn_update_dpp(xi, xi, 0x13C /*wave_ror:1*/, 0xF, 0xF, false);
    return __int_as_float(r);
}

__global__ __launch_bounds__(64) void dp_kernel(
    const float* __restrict__ lpT,
    const int* __restrict__ tlen, const int* __restrict__ mlen,
    float* __restrict__ alpha)
{
    const int b = blockIdx.x;
    const int l = threadIdx.x;          // 0..63

    const int tl   = tlen[b];
    const int ml   = mlen[b];
    const int tmax = ml - 1;            // last t index
    const int jt   = tl - 1;            // last j index
    const float inv_ml = 1.0f / (float)ml;

    const float* base = lpT + (size_t)b * MEL * TXT + l;

    // t=0 init: col0[j] = NEGV except j==0 -> lp[0][0]
    float r0 = base[0];                 // lpT[b][0][l] (coalesced; only lane0's used)
    const bool z = (l == 0);
    float cur0 = z ? r0 : NEGV;
    float cur1 = NEGV, cur2 = NEGV, cur3 = NEGV;

    if (tmax <= 0) {
        if (l == (jt & 63)) {
            float v = (jt >> 6) == 0 ? cur0 : NEGV;
            alpha[b] = v * inv_ml;
        }
        return;
    }

    // prefetch ring: 8 future rows x 4 chunks
    float buf[8][4];
#pragma unroll
    for (int i = 0; i < 8; ++i) {
        int tc = (1 + i <= tmax) ? (1 + i) : tmax;
        const float* p = base + (size_t)tc * TXT;
        buf[i][0] = p[0]; buf[i][1] = p[64]; buf[i][2] = p[128]; buf[i][3] = p[192];
    }

#define LSE_ADD(CUR, SH, LPC)                                  \
    {                                                          \
        float mx = fmaxf(CUR, SH);                             \
        float dd = CUR - SH;                                   \
        float ee = __expf(-fabsf(dd));                         \
        CUR = mx + __logf(1.0f + ee) + (LPC);                  \
    }

#define DP_CORE(L0, L1, L2, L3)                                \
    {                                                          \
        float sr0 = wave_ror1(cur0);                           \
        float sr1 = wave_ror1(cur1);                           \
        float sr2 = wave_ror1(cur2);                           \
        float sr3 = wave_ror1(cur3);                           \
        float sh0 = z ? NEGV : sr0;                            \
        float sh1 = z ? sr0 : sr1;                             \
        float sh2 = z ? sr1 : sr2;                             \
        float sh3 = z ? sr2 : sr3;                             \
        LSE_ADD(cur0, sh0, L0);                                \
        LSE_ADD(cur1, sh1, L1);                                \
        LSE_ADD(cur2, sh2, L2);                                \
        LSE_ADD(cur3, sh3, L3);                                \
    }

    int t = 1;
    for (; t + 7 <= tmax; t += 8) {
#pragma unroll
        for (int s = 0; s < 8; ++s) {
            float l0 = buf[s][0], l1 = buf[s][1], l2 = buf[s][2], l3 = buf[s][3];
            int tn = t + s + 8;
            int tc = (tn <= MEL - 1) ? tn : (MEL - 1);   // rows always exist
            const float* p = base + (size_t)tc * TXT;
            buf[s][0] = p[0]; buf[s][1] = p[64]; buf[s][2] = p[128]; buf[s][3] = p[192];
            DP_CORE(l0, l1, l2, l3);
        }
    }
    // tail (<8 steps), block-uniform branches
#pragma unroll
    for (int s = 0; s < 8; ++s) {
        if (t + s <= tmax) {
            float l0 = buf[s][0], l1 = buf[s][1], l2 = buf[s][2], l3 = buf[s][3];
            DP_CORE(l0, l1, l2, l3);
        }
    }
#undef DP_CORE
#undef LSE_ADD

    const int kf = jt >> 6;
    const int lf = jt & 63;
    float v = (kf == 0) ? cur0 : (kf == 1) ? cur1 : (kf == 2) ? cur2 : cur3;
    if (l == lf) alpha[b] = v * inv_ml;
}

// ---------------------------------------------------------------------------
// DP fallback (un-transposed reads) if ws too small — correctness safety net.
// ---------------------------------------------------------------------------
__global__ __launch_bounds__(256) void dp_kernel_fallback(
    const float* __restrict__ lp,
    const int* __restrict__ tlen, const int* __restrict__ mlen,
    float* __restrict__ alpha)
{
    const int b    = blockIdx.x;
    const int j    = threadIdx.x;
    const int lane = j & 63;
    const int w    = j >> 6;

    const int tl   = tlen[b];
    const int ml   = mlen[b];
    const int tmax = ml - 1;
    const int jt   = tl - 1;
    const float inv_ml = 1.0f / (float)ml;

    __shared__ float bnd[2][4];
    if (threadIdx.x < 8) bnd[threadIdx.x >> 2][threadIdx.x & 3] = NEGV;
    __syncthreads();

    float cur = (j == 0) ? lp[(size_t)(b * TXT) * MEL] : NEGV;
    if (tmax == 0) {
        if (j == jt) alpha[b] = cur * inv_ml;
        return;
    }
    int p = 0;
    for (int t = 1; t <= tmax; ++t) {
        float lpc = lp[((size_t)(b * TXT + j)) * MEL + t];
        float sh = __shfl_up(cur, 1);
        if (lane == 0) sh = (w > 0) ? bnd[p][w - 1] : NEGV;
        float mx = fmaxf(cur, sh);
        float dd = fminf(cur, sh) - mx;
        float nv = mx + __logf(1.0f + __expf(dd)) + lpc;
        if (lane == 63) bnd[p ^ 1][w] = nv;
        if (t == tmax && j == jt) alpha[b] = nv * inv_ml;
        cur = nv;
        __syncthreads();
        p ^= 1;
    }
}

// ---------------------------------------------------------------------------
// Reduce: loss = -mean_b(alpha[b])
// ---------------------------------------------------------------------------
__global__ void reduce_kernel(const float* __restrict__ alpha, float* __restrict__ out)
{
    const int tid = threadIdx.x;
    float v = (tid < B_) ? alpha[tid] : 0.f;
#pragma unroll
    for (int m = 16; m >= 1; m >>= 1) v += __shfl_xor(v, m);
    if (tid == 0) out[0] = -v / (float)B_;
}

// ---------------------------------------------------------------------------
extern "C" void kernel_launch(void* const* d_in, const int* in_sizes, int n_in,
                              void* d_out, int out_size, void* d_ws, size_t ws_size,
                              hipStream_t stream)
{
    const float* mu_logvar = (const float*)d_in[0];
    const float* melspec   = (const float*)d_in[1];
    const int*   tlen      = (const int*)d_in[2];
    const int*   mlen      = (const int*)d_in[3];
    float* out = (float*)d_out;
    float* ws  = (float*)d_ws;

    // ws layout (floats)
    const size_t IV_OFF    = 0;                        // 32*80*256 = 655360
    const size_t M2_OFF    = 655360;                   // 655360
    const size_t S_OFF     = 1310720;                  // 8192
    const size_t ALPHA_OFF = 1318912;                  // 32
    const size_t LPT_OFF   = 1318944;                  // 16,777,216 (67MB, optional)
    const size_t LPT_ELEMS = (size_t)B_ * MEL * TXT;

    float* IV    = ws + IV_OFF;
    float* M2    = ws + M2_OFF;
    float* S     = ws + S_OFF;
    float* alpha = ws + ALPHA_OFF;
    float* lpT   = ws + LPT_OFF;

    const bool use_lpT = ws_size >= (LPT_OFF + LPT_ELEMS) * sizeof(float);

    precompute_kernel<<<dim3(B_), dim3(256), 0, stream>>>(mu_logvar, IV, M2, S);

    logprob_kernel<<<dim3(MEL / 128, TXT / 64, B_), dim3(256), 0, stream>>>(
        melspec, IV, M2, S, out + 1, lpT, use_lpT ? 1 : 0);

    if (use_lpT) {
        dp_kernel<<<dim3(B_), dim3(64), 0, stream>>>(lpT, tlen, mlen, alpha);
    } else {
        dp_kernel_fallback<<<dim3(B_), dim3(256), 0, stream>>>(out + 1, tlen, mlen, alpha);
    }

    reduce_kernel<<<dim3(1), dim3(64), 0, stream>>>(alpha, out);
}

// Round 3
// 541.726 us; speedup vs baseline: 1.1966x; 1.1966x over previous
//
#include <hip/hip_runtime.h>
#include <cstddef>
#include <cstdint>

#define NEGV -1e30f

constexpr int B_    = 32;
constexpr int TXT   = 256;
constexpr int MEL   = 2048;
constexpr int NMEL  = 80;

// ---------------------------------------------------------------------------
// Kernel P: per (b,j): iv[c]=exp(-logvar), m2[c]=2*mu*iv, s = sum(mu^2*iv + logvar)
// Writes IV/M2 transposed to [b][c][j] for coalesced LDS staging in kernel 1.
// ---------------------------------------------------------------------------
__global__ __launch_bounds__(256) void precompute_kernel(
    const float* __restrict__ mu_logvar,
    float* __restrict__ IV, float* __restrict__ M2, float* __restrict__ S)
{
    const int b = blockIdx.x;
    const int j = threadIdx.x;
    const float* row = mu_logvar + (size_t)(b * TXT + j) * (2 * NMEL);
    float s = 0.f;
    for (int c = 0; c < NMEL; ++c) {
        float mu = row[c];
        float lv = row[NMEL + c];
        float iv = expf(-lv);
        IV[(b * NMEL + c) * TXT + j] = iv;
        M2[(b * NMEL + c) * TXT + j] = 2.0f * mu * iv;
        s += mu * mu * iv + lv;
    }
    S[b * TXT + j] = s;
}

// ---------------------------------------------------------------------------
// Kernel 1: log_prob. Tile 64 j x 128 t per block (256 threads).
// Dual-writes: out[b][j][t] (at d_out+1) and lpT[b][t][j] in ws.
// ---------------------------------------------------------------------------
__global__ __launch_bounds__(256) void logprob_kernel(
    const float* __restrict__ mel,
    const float* __restrict__ IV, const float* __restrict__ M2,
    const float* __restrict__ S,
    float* __restrict__ out1,          // d_out + 1 (log_prob region)
    float* __restrict__ lpT,           // ws transposed copy [b][t][j]
    int write_lpT)
{
    const int tt0 = blockIdx.x * 128;
    const int j0  = blockIdx.y * 64;
    const int b   = blockIdx.z;
    const int tx  = threadIdx.x & 15;
    const int ty  = threadIdx.x >> 4;

    __shared__ float sIV[NMEL][64];
    __shared__ float sM2[NMEL][64];

    for (int idx = threadIdx.x; idx < NMEL * 64; idx += 256) {
        int c  = idx >> 6;
        int jj = idx & 63;
        sIV[c][jj] = IV[(b * NMEL + c) * TXT + j0 + jj];
        sM2[c][jj] = M2[(b * NMEL + c) * TXT + j0 + jj];
    }
    __syncthreads();

    float acc[4][8];
#pragma unroll
    for (int a = 0; a < 4; ++a)
#pragma unroll
        for (int d = 0; d < 8; ++d) acc[a][d] = 0.f;

    const float* melb = mel + (size_t)b * NMEL * MEL + tt0 + tx;

#pragma unroll 2
    for (int c = 0; c < NMEL; ++c) {
        float x[8];
#pragma unroll
        for (int d = 0; d < 8; ++d) x[d] = melb[(size_t)c * MEL + 16 * d];
        float4 iv = *(const float4*)&sIV[c][ty * 4];
        float4 m2 = *(const float4*)&sM2[c][ty * 4];
        float ivr[4] = {iv.x, iv.y, iv.z, iv.w};
        float m2r[4] = {m2.x, m2.y, m2.z, m2.w};
#pragma unroll
        for (int a = 0; a < 4; ++a) {
#pragma unroll
            for (int d = 0; d < 8; ++d) {
                float tmp = fmaf(ivr[a], x[d], -m2r[a]);
                acc[a][d] = fmaf(tmp, x[d], acc[a][d]);
            }
        }
    }

    const float c0 = -0.5f / (float)NMEL;
    float4 sj = *(const float4*)&S[b * TXT + j0 + ty * 4];
    float sjr[4] = {sj.x, sj.y, sj.z, sj.w};

#pragma unroll
    for (int a = 0; a < 4; ++a) {
        const int j = j0 + ty * 4 + a;
        float* ob = out1 + (size_t)(b * TXT + j) * MEL + tt0 + tx;
#pragma unroll
        for (int d = 0; d < 8; ++d) {
            float v = c0 * (acc[a][d] + sjr[a]);
            ob[16 * d] = v;
            if (write_lpT) {
                lpT[((size_t)b * MEL + tt0 + tx + 16 * d) * TXT + j] = v;
            }
        }
    }
}

// ---------------------------------------------------------------------------
// DP kernel v3: one wave per batch; lane l owns j = 4l..4l+3 (one float4).
// One global_load_dwordx4 per step. j-1 dependency: within-lane for 3 of 4
// elements; one DPP wave_ror:1 on the .w component for the lane boundary.
// 16-deep NAMED-REGISTER prefetch ring (no arrays -> no scratch), manual
// 16x unroll. lpT padded by 16 rows so no clamp on prefetch addresses.
// ---------------------------------------------------------------------------
__device__ __forceinline__ float wave_ror1(float x) {
    int xi = __float_as_int(x);
    int r  = __builtin_amdgcn_update_dpp(xi, xi, 0x13C /*wave_ror:1*/, 0xF, 0xF, false);
    return __int_as_float(r);
}

__device__ __forceinline__ float lse2(float a, float b) {
    float mx = fmaxf(a, b);
    float d  = -fabsf(a - b);
    return mx + __logf(1.0f + __expf(d));
}

__global__ __launch_bounds__(64) void dp_kernel(
    const float* __restrict__ lpT,
    const int* __restrict__ tlen, const int* __restrict__ mlen,
    float* __restrict__ alpha)
{
    const int b = blockIdx.x;
    const int l = threadIdx.x;          // 0..63

    const int tl   = tlen[b];
    const int ml   = mlen[b];
    const int tmax = ml - 1;            // last t index (>= 1023 for this shape)
    const int jt   = tl - 1;            // last j index
    const float inv_ml = 1.0f / (float)ml;

    // row stride in float4 units = TXT/4 = 64
    const float4* base = (const float4*)(lpT + (size_t)b * MEL * TXT) + l;
    const bool z = (l == 0);

    // t = 0 init
    float4 ld0 = base[0];
    float c0 = z ? ld0.x : NEGV;
    float c1 = NEGV, c2 = NEGV, c3 = NEGV;

    if (tmax <= 0) {
        const int lf = jt >> 2, ef = jt & 3;
        float v = (ef == 0) ? c0 : NEGV;
        if (l == lf) alpha[b] = v * inv_ml;
        return;
    }

    // named 16-deep ring: slot i holds row t+i (initially rows 1..16)
    float4 r0  = base[(size_t) 1 * 64];
    float4 r1  = base[(size_t) 2 * 64];
    float4 r2  = base[(size_t) 3 * 64];
    float4 r3  = base[(size_t) 4 * 64];
    float4 r4  = base[(size_t) 5 * 64];
    float4 r5  = base[(size_t) 6 * 64];
    float4 r6  = base[(size_t) 7 * 64];
    float4 r7  = base[(size_t) 8 * 64];
    float4 r8  = base[(size_t) 9 * 64];
    float4 r9  = base[(size_t)10 * 64];
    float4 r10 = base[(size_t)11 * 64];
    float4 r11 = base[(size_t)12 * 64];
    float4 r12 = base[(size_t)13 * 64];
    float4 r13 = base[(size_t)14 * 64];
    float4 r14 = base[(size_t)15 * 64];
    float4 r15 = base[(size_t)16 * 64];

#define DP_CORE(LP)                                            \
    {                                                          \
        float sw = wave_ror1(c3);                              \
        sw = z ? NEGV : sw;                                    \
        float n0 = lse2(c0, sw) + (LP).x;                      \
        float n1 = lse2(c1, c0) + (LP).y;                      \
        float n2 = lse2(c2, c1) + (LP).z;                      \
        float n3 = lse2(c3, c2) + (LP).w;                      \
        c0 = n0; c1 = n1; c2 = n2; c3 = n3;                    \
    }

// consume slot RS (row t+S), refill with row t+S+16 (lpT padded -> in bounds)
#define DP_STEP(RS, S)                                         \
    {                                                          \
        float4 lp = RS;                                        \
        RS = base[(size_t)(t + (S) + 16) * 64];                \
        DP_CORE(lp);                                           \
    }

    int t = 1;
    for (; t + 15 <= tmax; t += 16) {
        DP_STEP(r0,  0)  DP_STEP(r1,  1)  DP_STEP(r2,  2)  DP_STEP(r3,  3)
        DP_STEP(r4,  4)  DP_STEP(r5,  5)  DP_STEP(r6,  6)  DP_STEP(r7,  7)
        DP_STEP(r8,  8)  DP_STEP(r9,  9)  DP_STEP(r10, 10) DP_STEP(r11, 11)
        DP_STEP(r12, 12) DP_STEP(r13, 13) DP_STEP(r14, 14) DP_STEP(r15, 15)
    }

    // tail: <=15 remaining steps, uniform conditions, slots already hold rows t..t+15
#define DP_TAIL(RS, S)                                         \
    if (t + (S) <= tmax) { DP_CORE(RS); }

    DP_TAIL(r0,  0)  DP_TAIL(r1,  1)  DP_TAIL(r2,  2)  DP_TAIL(r3,  3)
    DP_TAIL(r4,  4)  DP_TAIL(r5,  5)  DP_TAIL(r6,  6)  DP_TAIL(r7,  7)
    DP_TAIL(r8,  8)  DP_TAIL(r9,  9)  DP_TAIL(r10, 10) DP_TAIL(r11, 11)
    DP_TAIL(r12, 12) DP_TAIL(r13, 13) DP_TAIL(r14, 14)

#undef DP_TAIL
#undef DP_STEP
#undef DP_CORE

    const int lf = jt >> 2;
    const int ef = jt & 3;
    float v = (ef == 0) ? c0 : (ef == 1) ? c1 : (ef == 2) ? c2 : c3;
    if (l == lf) alpha[b] = v * inv_ml;
}

// ---------------------------------------------------------------------------
// DP fallback (un-transposed reads) if ws too small — correctness safety net.
// ---------------------------------------------------------------------------
__global__ __launch_bounds__(256) void dp_kernel_fallback(
    const float* __restrict__ lp,
    const int* __restrict__ tlen, const int* __restrict__ mlen,
    float* __restrict__ alpha)
{
    const int b    = blockIdx.x;
    const int j    = threadIdx.x;
    const int lane = j & 63;
    const int w    = j >> 6;

    const int tl   = tlen[b];
    const int ml   = mlen[b];
    const int tmax = ml - 1;
    const int jt   = tl - 1;
    const float inv_ml = 1.0f / (float)ml;

    __shared__ float bnd[2][4];
    if (threadIdx.x < 8) bnd[threadIdx.x >> 2][threadIdx.x & 3] = NEGV;
    __syncthreads();

    float cur = (j == 0) ? lp[(size_t)(b * TXT) * MEL] : NEGV;
    if (tmax == 0) {
        if (j == jt) alpha[b] = cur * inv_ml;
        return;
    }
    int p = 0;
    for (int t = 1; t <= tmax; ++t) {
        float lpc = lp[((size_t)(b * TXT + j)) * MEL + t];
        float sh = __shfl_up(cur, 1);
        if (lane == 0) sh = (w > 0) ? bnd[p][w - 1] : NEGV;
        float mx = fmaxf(cur, sh);
        float dd = fminf(cur, sh) - mx;
        float nv = mx + __logf(1.0f + __expf(dd)) + lpc;
        if (lane == 63) bnd[p ^ 1][w] = nv;
        if (t == tmax && j == jt) alpha[b] = nv * inv_ml;
        cur = nv;
        __syncthreads();
        p ^= 1;
    }
}

// ---------------------------------------------------------------------------
// Reduce: loss = -mean_b(alpha[b])
// ---------------------------------------------------------------------------
__global__ void reduce_kernel(const float* __restrict__ alpha, float* __restrict__ out)
{
    const int tid = threadIdx.x;
    float v = (tid < B_) ? alpha[tid] : 0.f;
#pragma unroll
    for (int m = 16; m >= 1; m >>= 1) v += __shfl_xor(v, m);
    if (tid == 0) out[0] = -v / (float)B_;
}

// ---------------------------------------------------------------------------
extern "C" void kernel_launch(void* const* d_in, const int* in_sizes, int n_in,
                              void* d_out, int out_size, void* d_ws, size_t ws_size,
                              hipStream_t stream)
{
    const float* mu_logvar = (const float*)d_in[0];
    const float* melspec   = (const float*)d_in[1];
    const int*   tlen      = (const int*)d_in[2];
    const int*   mlen      = (const int*)d_in[3];
    float* out = (float*)d_out;
    float* ws  = (float*)d_ws;

    // ws layout (floats)
    const size_t IV_OFF    = 0;                        // 32*80*256 = 655360
    const size_t M2_OFF    = 655360;                   // 655360
    const size_t S_OFF     = 1310720;                  // 8192
    const size_t ALPHA_OFF = 1318912;                  // 32
    const size_t LPT_OFF   = 1318944;                  // 16,777,216 + pad
    const size_t LPT_ELEMS = (size_t)B_ * MEL * TXT;
    const size_t LPT_PAD   = (size_t)16 * TXT;         // 16 rows prefetch slack

    float* IV    = ws + IV_OFF;
    float* M2    = ws + M2_OFF;
    float* S     = ws + S_OFF;
    float* alpha = ws + ALPHA_OFF;
    float* lpT   = ws + LPT_OFF;

    const bool use_lpT = ws_size >= (LPT_OFF + LPT_ELEMS + LPT_PAD) * sizeof(float);

    precompute_kernel<<<dim3(B_), dim3(256), 0, stream>>>(mu_logvar, IV, M2, S);

    logprob_kernel<<<dim3(MEL / 128, TXT / 64, B_), dim3(256), 0, stream>>>(
        melspec, IV, M2, S, out + 1, lpT, use_lpT ? 1 : 0);

    if (use_lpT) {
        dp_kernel<<<dim3(B_), dim3(64), 0, stream>>>(lpT, tlen, mlen, alpha);
    } else {
        dp_kernel_fallback<<<dim3(B_), dim3(256), 0, stream>>>(out + 1, tlen, mlen, alpha);
    }

    reduce_kernel<<<dim3(1), dim3(64), 0, stream>>>(alpha, out);
}